// Round 7
// baseline (150.579 us; speedup 1.0000x reference)
//
#include <hip/hip_runtime.h>

// Problem constants (fixed by the reference file)
#define BATCH 2048
#define MM    256
#define DD    1024

// Tiling: 128b x 64m x 32d per block, ONE barrier, 8 jobs/CU (~6 resident).
#define BB 128
#define BM 64
#define DC 32
#define SD  (DD / DC)      // 32 d-blocks
#define NBT (BATCH / BB)   // 16 b-blocks
#define NMT (MM / BM)      // 4 m-blocks
#define LXS (BB + 4)       // padded LDS stride: 132 words
#define LRS (BM + 4)       // 68 words

#define LOG2E 1.4426950408889634f
#define LN2   0.6931471805599453f

typedef float v2f __attribute__((ext_vector_type(2)));

// ---- exact log2 bookkeeping via frexp (full-rate VALU) ----
__device__ __forceinline__ float fr_mant(float x) {
    return __builtin_amdgcn_frexp_mantf(x);
}
__device__ __forceinline__ int fr_exp(float x) {
    return __builtin_amdgcn_frexp_expf(x);
}

// bf16 helpers (RNE)
__device__ __forceinline__ unsigned short f2bf(float f) {
    unsigned u = __float_as_uint(f);
    u += 0x7FFFu + ((u >> 16) & 1u);
    return (unsigned short)(u >> 16);
}
__device__ __forceinline__ float bf2f(unsigned short u) {
    return __uint_as_float((unsigned)u << 16);
}

// ---------------------------------------------------------------------------
// Kernel A: r[m][d] = e^z - 1 (natural [m][d]);  lik = q*(1 + x*r), q = 1-p
// cst[m] = sum_d log2 q[m][d] + log2 softmax(W)[m]
// ---------------------------------------------------------------------------
__global__ __launch_bounds__(256) void precomp_kernel(
        const float* __restrict__ P, const float* __restrict__ Wv,
        float* __restrict__ rbuf, float* __restrict__ cst) {
    const int m = blockIdx.x;
    const int t = threadIdx.x;
    const int lane = t & 63, wid = t >> 6;

    float4 z = ((const float4*)(P + (size_t)m * DD))[t];
    float e0 = __expf(z.x), e1 = __expf(z.y), e2 = __expf(z.z), e3 = __expf(z.w);
    ((float4*)(rbuf + (size_t)m * DD))[t] =
        make_float4(e0 - 1.f, e1 - 1.f, e2 - 1.f, e3 - 1.f);
    float part = -(__log2f(1.f + e0) + __log2f(1.f + e1) +
                   __log2f(1.f + e2) + __log2f(1.f + e3));

    __shared__ float smA[4], smB[4];

    #pragma unroll
    for (int o = 32; o; o >>= 1) part += __shfl_xor(part, o);
    if (lane == 0) smA[wid] = part;

    float w = Wv[t];
    float mx = w;
    #pragma unroll
    for (int o = 32; o; o >>= 1) mx = fmaxf(mx, __shfl_xor(mx, o));
    if (lane == 0) smB[wid] = mx;
    __syncthreads();

    float rowc = smA[0] + smA[1] + smA[2] + smA[3];
    float gmx  = fmaxf(fmaxf(smB[0], smB[1]), fmaxf(smB[2], smB[3]));

    float se = __expf(w - gmx);
    #pragma unroll
    for (int o = 32; o; o >>= 1) se += __shfl_xor(se, o);
    __syncthreads();
    if (lane == 0) smA[wid] = se;
    __syncthreads();

    if (t == 0) {
        float sum = smA[0] + smA[1] + smA[2] + smA[3];
        cst[m] = rowc + (Wv[m] - gmx) * LOG2E - __log2f(sum);
    }
}

// ---------------------------------------------------------------------------
// Kernel B: pbuf[d_id][b][m] (bf16) = sum_{d in 32-block} log2(1 + x*r)
// Small monolithic tile: coalesced load -> transposed LDS scatter -> ONE
// barrier -> unbroken 32-kc packed compute -> bf16 store. 25.6 KB LDS gives
// ~6 resident blocks/CU with 8 jobs/CU: staging of incoming blocks overlaps
// compute of resident ones; no recurring barrier convoy (one barrier/block).
// ---------------------------------------------------------------------------
__global__ __launch_bounds__(256, 6) void main_kernel(
        const float* __restrict__ x, const float* __restrict__ rbuf,
        unsigned short* __restrict__ pbuf) {
    __shared__ __align__(16) float lx[DC * LXS];   // [32 kc][128 b] padded
    __shared__ __align__(16) float lr[DC * LRS];   // [32 kc][64 m]  padded

    const int tid = threadIdx.x;
    const int tx = tid & 15;    // m
    const int ty = tid >> 4;    // b
    const int m_id = blockIdx.x;
    const int b_id = blockIdx.y;
    const int d_id = blockIdx.z;
    const int m0 = m_id * BM;
    const int b0 = b_id * BB;
    const int d0 = d_id * DC;

    // stage x tile: 128 rows x 8 float4 = 1024 f4, 4 per thread
    #pragma unroll
    for (int l = 0; l < 4; ++l) {
        int i4 = tid + 256 * l;
        int row = i4 >> 3;          // 0..127
        int seg = i4 & 7;           // 0..7
        float4 v = *(const float4*)(x + (size_t)(b0 + row) * DD + d0 + seg * 4);
        lx[(seg * 4 + 0) * LXS + row] = v.x;
        lx[(seg * 4 + 1) * LXS + row] = v.y;
        lx[(seg * 4 + 2) * LXS + row] = v.z;
        lx[(seg * 4 + 3) * LXS + row] = v.w;
    }
    // stage r tile: 64 rows x 8 float4 = 512 f4, 2 per thread
    #pragma unroll
    for (int l = 0; l < 2; ++l) {
        int i4 = tid + 256 * l;
        int row = i4 >> 3;          // 0..63
        int seg = i4 & 7;
        float4 v = *(const float4*)(rbuf + (size_t)(m0 + row) * DD + d0 + seg * 4);
        lr[(seg * 4 + 0) * LRS + row] = v.x;
        lr[(seg * 4 + 1) * LRS + row] = v.y;
        lr[(seg * 4 + 2) * LRS + row] = v.z;
        lr[(seg * 4 + 3) * LRS + row] = v.w;
    }

    const v2f one2 = {1.0f, 1.0f};
    v2f prod[4][4];
    int acce[8][4];
    #pragma unroll
    for (int i2 = 0; i2 < 4; ++i2)
        #pragma unroll
        for (int j = 0; j < 4; ++j) prod[i2][j] = one2;
    #pragma unroll
    for (int i = 0; i < 8; ++i)
        #pragma unroll
        for (int j = 0; j < 4; ++j) acce[i][j] = 0;

    __syncthreads();   // the only barrier in this block's life

    const float4* xa = (const float4*)(lx + 8 * ty);  // +kc*33 f4 (132 words)
    const float4* rb = (const float4*)(lr + 4 * tx);  // +kc*17 f4 (68 words)

    #pragma unroll
    for (int g = 0; g < 4; ++g) {
        #pragma unroll
        for (int s = 0; s < 8; ++s) {
            const int kc = g * 8 + s;
            float4 x0 = xa[kc * 33];
            float4 x1 = xa[kc * 33 + 1];
            float4 rv = rb[kc * 17];
            v2f xp2[4] = {{x0.x, x0.y}, {x0.z, x0.w},
                          {x1.x, x1.y}, {x1.z, x1.w}};
            float rf[4] = {rv.x, rv.y, rv.z, rv.w};
            #pragma unroll
            for (int j = 0; j < 4; ++j) {
                v2f rr = {rf[j], rf[j]};
                #pragma unroll
                for (int i2 = 0; i2 < 4; ++i2) {
                    v2f tt = __builtin_elementwise_fma(xp2[i2], rr, one2);
                    prod[i2][j] = prod[i2][j] * tt;
                }
            }
        }
        // close group of 8 d: exact exponent extraction (range-safe:
        // t in [~0.004, ~250] -> 8-products within fp32 normal range)
        #pragma unroll
        for (int i2 = 0; i2 < 4; ++i2)
            #pragma unroll
            for (int j = 0; j < 4; ++j) {
                v2f p = prod[i2][j];
                acce[2 * i2 + 0][j] += fr_exp(p.x);
                acce[2 * i2 + 1][j] += fr_exp(p.y);
                p.x = fr_mant(p.x);
                p.y = fr_mant(p.y);
                prod[i2][j] = p;
            }
    }

    // epilogue: bf16 partials, coalesced ushort4 stores
    unsigned short* pb = pbuf + ((size_t)d_id * BATCH + (size_t)b0) * MM + m0;
    #pragma unroll
    for (int i2 = 0; i2 < 4; ++i2)
        #pragma unroll
        for (int h = 0; h < 2; ++h) {
            const int i = 2 * i2 + h;
            float f0 = (float)acce[i][0] + __log2f(h ? prod[i2][0].y : prod[i2][0].x);
            float f1 = (float)acce[i][1] + __log2f(h ? prod[i2][1].y : prod[i2][1].x);
            float f2 = (float)acce[i][2] + __log2f(h ? prod[i2][2].y : prod[i2][2].x);
            float f3 = (float)acce[i][3] + __log2f(h ? prod[i2][3].y : prod[i2][3].x);
            ushort4 w;
            w.x = f2bf(f0); w.y = f2bf(f1); w.z = f2bf(f2); w.w = f2bf(f3);
            *(ushort4*)&pb[(size_t)(8 * ty + i) * MM + 4 * tx] = w;
        }
}

// ---------------------------------------------------------------------------
// Kernel C: sum 32 bf16 partials + cst, per-batch logsumexp over m.
// One wave per batch; lane covers 4 m's.
// ---------------------------------------------------------------------------
__global__ __launch_bounds__(256) void finalize_kernel(
        const unsigned short* __restrict__ pbuf, const float* __restrict__ cst,
        float* __restrict__ out) {
    const int lane = threadIdx.x & 63;
    const int w = threadIdx.x >> 6;
    const int b = blockIdx.x * 4 + w;

    float4 v = ((const float4*)cst)[lane];
    const ushort4* pb = (const ushort4*)pbuf + (size_t)b * (MM / 4) + lane;
    #pragma unroll
    for (int s = 0; s < SD; ++s) {
        ushort4 t = pb[(size_t)s * BATCH * (MM / 4)];
        v.x += bf2f(t.x); v.y += bf2f(t.y); v.z += bf2f(t.z); v.w += bf2f(t.w);
    }

    float mx = fmaxf(fmaxf(v.x, v.y), fmaxf(v.z, v.w));
    #pragma unroll
    for (int o = 32; o; o >>= 1) mx = fmaxf(mx, __shfl_xor(mx, o));

    float s = exp2f(v.x - mx) + exp2f(v.y - mx) + exp2f(v.z - mx) + exp2f(v.w - mx);
    #pragma unroll
    for (int o = 32; o; o >>= 1) s += __shfl_xor(s, o);

    if (lane == 0) out[b] = LN2 * (mx + __log2f(s));
}

extern "C" void kernel_launch(void* const* d_in, const int* in_sizes, int n_in,
                              void* d_out, int out_size, void* d_ws, size_t ws_size,
                              hipStream_t stream) {
    const float* x  = (const float*)d_in[0];
    const float* Wv = (const float*)d_in[1];
    const float* P  = (const float*)d_in[2];

    // ws layout: [rbuf 1MiB][cst 1KiB][pbuf bf16 32*2048*256*2 = 32MiB] ~ 33.1MiB
    // (fits: round-1's 34.6 MiB footprint passed)
    float* ws   = (float*)d_ws;
    float* rbuf = ws;
    float* cst  = rbuf + (size_t)MM * DD;
    unsigned short* pbuf = (unsigned short*)(cst + MM);

    precomp_kernel<<<MM, 256, 0, stream>>>(P, Wv, rbuf, cst);
    dim3 gB(NMT, NBT, SD);
    main_kernel<<<gB, 256, 0, stream>>>(x, rbuf, pbuf);
    finalize_kernel<<<BATCH / 4, 256, 0, stream>>>(pbuf, cst, (float*)d_out);
}

// Round 8
// 120.396 us; speedup vs baseline: 1.2507x; 1.2507x over previous
//
#include <hip/hip_runtime.h>

// Problem constants (fixed by the reference file)
#define BATCH 2048
#define MM    256
#define DD    1024

// Tiling: 128b x 64m x 64d per block; KC=16 stages, async-DMA double buffer.
#define BB 128
#define BM 64
#define DC 64
#define KC 16
#define SD  (DD / DC)      // 16 d-blocks
#define NBT (BATCH / BB)   // 16 b-blocks
#define NMT (MM / BM)      // 4 m-blocks
#define XS_TILE (DC * BB)  // 8192 floats (global, transposed [kc][b])
#define RS_TILE (DC * BM)  // 4096 floats (global, transposed [kc][m])
#define XSTG (KC * BB)     // 2048 floats = 8 KB per stage
#define RSTG (KC * BM)     // 1024 floats = 4 KB per stage

#define LOG2E 1.4426950408889634f
#define LN2   0.6931471805599453f

typedef float v2f __attribute__((ext_vector_type(2)));

// ---- exact log2 bookkeeping via frexp (full-rate VALU) ----
__device__ __forceinline__ float fr_mant(float x) {
    return __builtin_amdgcn_frexp_mantf(x);
}
__device__ __forceinline__ int fr_exp(float x) {
    return __builtin_amdgcn_frexp_expf(x);
}

// bf16 helpers (RNE)
__device__ __forceinline__ unsigned short f2bf(float f) {
    unsigned u = __float_as_uint(f);
    u += 0x7FFFu + ((u >> 16) & 1u);
    return (unsigned short)(u >> 16);
}
__device__ __forceinline__ float bf2f(unsigned short u) {
    return __uint_as_float((unsigned)u << 16);
}

// async global->LDS, 16 B per lane; lds dest = wave-uniform base + lane*16
__device__ __forceinline__ void gl_lds16(const float* g, float* l) {
    __builtin_amdgcn_global_load_lds(
        (const __attribute__((address_space(1))) unsigned int*)g,
        (__attribute__((address_space(3))) unsigned int*)l, 16, 0, 0);
}

// ---------------------------------------------------------------------------
// Kernel P (fused prep, r6-proven): blocks [0,MM) per-m precompute + scatter
// r into rs tile order; blocks [MM, MM+NBT*SD) transpose x into xs tiles.
//   xs tile(b_id,d_id)[kc][brow] = x[b_id*128+brow][d_id*64+kc]
//   rs tile(m_id,d_id)[kc][mrow] = e^{P[m][d]} - 1
//   cst[m] = sum_d log2 q[m][d] + log2 softmax(W)[m],  q = 1/(1+e^P)
// ---------------------------------------------------------------------------
__global__ __launch_bounds__(256) void prep_kernel(
        const float* __restrict__ x, const float* __restrict__ P,
        const float* __restrict__ Wv, float* __restrict__ xs,
        float* __restrict__ rs, float* __restrict__ cst) {
    __shared__ float sh[128 * 65];
    const int tid = threadIdx.x;

    if (blockIdx.x >= MM) {
        const int idx = blockIdx.x - MM;
        const int bx = idx >> 4, by = idx & 15;
        const float* src = x + (size_t)bx * BB * DD + by * DC;
        float* dst = xs + ((size_t)bx * SD + by) * XS_TILE;

        #pragma unroll
        for (int k = 0; k < 8; ++k) {
            int i4 = tid + 256 * k;
            int row = i4 >> 4, c4 = i4 & 15;
            float4 v = *(const float4*)(src + (size_t)row * DD + c4 * 4);
            sh[row * 65 + c4 * 4 + 0] = v.x;
            sh[row * 65 + c4 * 4 + 1] = v.y;
            sh[row * 65 + c4 * 4 + 2] = v.z;
            sh[row * 65 + c4 * 4 + 3] = v.w;
        }
        __syncthreads();
        #pragma unroll
        for (int k = 0; k < 8; ++k) {
            int o4 = tid + 256 * k;
            int kc = o4 >> 5;
            int b4 = o4 & 31;
            float4 w;
            w.x = sh[(b4 * 4 + 0) * 65 + kc];
            w.y = sh[(b4 * 4 + 1) * 65 + kc];
            w.z = sh[(b4 * 4 + 2) * 65 + kc];
            w.w = sh[(b4 * 4 + 3) * 65 + kc];
            ((float4*)dst)[o4] = w;
        }
        return;
    }

    const int m = blockIdx.x;
    const int lane = tid & 63, wid = tid >> 6;
    float* smA = sh;
    float* smB = sh + 4;

    float4 z = ((const float4*)(P + (size_t)m * DD))[tid];
    float e0 = __expf(z.x), e1 = __expf(z.y), e2 = __expf(z.z), e3 = __expf(z.w);

    {
        const int d_id = tid >> 4;
        const int kc0  = (4 * tid) & 63;
        float* rt = rs + ((size_t)(m >> 6) * SD + d_id) * RS_TILE + (m & 63);
        rt[(size_t)(kc0 + 0) * BM] = e0 - 1.f;
        rt[(size_t)(kc0 + 1) * BM] = e1 - 1.f;
        rt[(size_t)(kc0 + 2) * BM] = e2 - 1.f;
        rt[(size_t)(kc0 + 3) * BM] = e3 - 1.f;
    }

    float part = -(__log2f(1.f + e0) + __log2f(1.f + e1) +
                   __log2f(1.f + e2) + __log2f(1.f + e3));
    #pragma unroll
    for (int o = 32; o; o >>= 1) part += __shfl_xor(part, o);
    if (lane == 0) smA[wid] = part;

    float w = Wv[tid];
    float mx = w;
    #pragma unroll
    for (int o = 32; o; o >>= 1) mx = fmaxf(mx, __shfl_xor(mx, o));
    if (lane == 0) smB[wid] = mx;
    __syncthreads();

    float rowc = smA[0] + smA[1] + smA[2] + smA[3];
    float gmx  = fmaxf(fmaxf(smB[0], smB[1]), fmaxf(smB[2], smB[3]));

    float se = __expf(w - gmx);
    #pragma unroll
    for (int o = 32; o; o >>= 1) se += __shfl_xor(se, o);
    __syncthreads();
    if (lane == 0) smA[wid] = se;
    __syncthreads();

    if (tid == 0) {
        float sum = smA[0] + smA[1] + smA[2] + smA[3];
        cst[m] = rowc + (Wv[m] - gmx) * LOG2E - __log2f(sum);
    }
}

// ---------------------------------------------------------------------------
// Kernel B: pbuf[d_id][b][m] (bf16) = sum_{d in 64-block} log2(1 + x*r)
// Async-DMA double-buffered K-loop: per stage, ONE __syncthreads, then issue
// next stage's global_load_lds (into the other buffer) and compute current —
// each prefetch gets a full stage of compute as latency cover. No ds_writes,
// no VGPR staging round-trip. 24 KB LDS + <=128 VGPR -> whole 1024-block grid
// co-resident at 4 blocks/CU.
// ---------------------------------------------------------------------------
__global__ __launch_bounds__(256, 4) void main_kernel(
        const float* __restrict__ xs, const float* __restrict__ rs,
        unsigned short* __restrict__ pbuf) {
    __shared__ __align__(16) float lx[2][XSTG];   // [16 kc][128 b] x2 = 16 KB
    __shared__ __align__(16) float lr[2][RSTG];   // [16 kc][64 m]  x2 =  8 KB

    const int tid  = threadIdx.x;
    const int lane = tid & 63;
    const int wv   = tid >> 6;
    const int tx = tid & 15;    // m
    const int ty = tid >> 4;    // b
    const int m_id = blockIdx.x;
    const int b_id = blockIdx.y;
    const int d_id = blockIdx.z;

    const float* xg = xs + ((size_t)b_id * SD + d_id) * XS_TILE;
    const float* rg = rs + ((size_t)m_id * SD + d_id) * RS_TILE;

    // issue stage 0 DMA
    {
        const float* xsrc = xg;
        #pragma unroll
        for (int k = 0; k < 2; ++k) {
            const int off = (wv * 2 + k) * 256;
            gl_lds16(xsrc + off + lane * 4, &lx[0][off]);
        }
        gl_lds16(rg + wv * 256 + lane * 4, &lr[0][wv * 256]);
    }

    const v2f one2 = {1.0f, 1.0f};
    v2f prod[4][4];
    int acce[8][4];
    #pragma unroll
    for (int i2 = 0; i2 < 4; ++i2)
        #pragma unroll
        for (int j = 0; j < 4; ++j) prod[i2][j] = one2;
    #pragma unroll
    for (int i = 0; i < 8; ++i)
        #pragma unroll
        for (int j = 0; j < 4; ++j) acce[i][j] = 0;

    #pragma unroll
    for (int c = 0; c < DC / KC; ++c) {
        __syncthreads();   // drains vmcnt -> buffer c&1 resident
        // issue next stage's DMA into the other buffer (WAR-safe: that
        // buffer's reads completed before the barrier above)
        if (c + 1 < DC / KC) {
            const int nb = (c + 1) & 1;
            const float* xsrc = xg + (c + 1) * XSTG;
            const float* rsrc = rg + (c + 1) * RSTG;
            #pragma unroll
            for (int k = 0; k < 2; ++k) {
                const int off = (wv * 2 + k) * 256;
                gl_lds16(xsrc + off + lane * 4, &lx[nb][off]);
            }
            gl_lds16(rsrc + wv * 256 + lane * 4, &lr[nb][wv * 256]);
        }

        const float* xa = &lx[c & 1][8 * ty];   // +kc*128; 16-lane broadcast
        const float* rp = &lr[c & 1][4 * tx];   // +kc*64; 2-way alias (free)

        #pragma unroll
        for (int g = 0; g < 2; ++g) {
            #pragma unroll
            for (int s = 0; s < 8; ++s) {
                const int kc = g * 8 + s;
                float4 x0 = *(const float4*)(xa + kc * BB);
                float4 x1 = *(const float4*)(xa + kc * BB + 4);
                float4 rv = *(const float4*)(rp + kc * BM);
                v2f xp2[4] = {{x0.x, x0.y}, {x0.z, x0.w},
                              {x1.x, x1.y}, {x1.z, x1.w}};
                float rf[4] = {rv.x, rv.y, rv.z, rv.w};
                #pragma unroll
                for (int j = 0; j < 4; ++j) {
                    v2f rr = {rf[j], rf[j]};
                    #pragma unroll
                    for (int i2 = 0; i2 < 4; ++i2) {
                        v2f tt = __builtin_elementwise_fma(xp2[i2], rr, one2);
                        prod[i2][j] = prod[i2][j] * tt;
                    }
                }
            }
            // close group of 8 d: exact exponent extraction (range-safe:
            // t in [~0.004, ~250] -> 8-products within fp32 normal range)
            #pragma unroll
            for (int i2 = 0; i2 < 4; ++i2)
                #pragma unroll
                for (int j = 0; j < 4; ++j) {
                    v2f p = prod[i2][j];
                    acce[2 * i2 + 0][j] += fr_exp(p.x);
                    acce[2 * i2 + 1][j] += fr_exp(p.y);
                    p.x = fr_mant(p.x);
                    p.y = fr_mant(p.y);
                    prod[i2][j] = p;
                }
        }
    }

    // epilogue: bf16 partials, coalesced ushort4 stores
    unsigned short* pb = pbuf + ((size_t)d_id * BATCH + (size_t)b_id * BB) * MM
                              + (size_t)m_id * BM;
    #pragma unroll
    for (int i2 = 0; i2 < 4; ++i2)
        #pragma unroll
        for (int h = 0; h < 2; ++h) {
            const int i = 2 * i2 + h;
            float f0 = (float)acce[i][0] + __log2f(h ? prod[i2][0].y : prod[i2][0].x);
            float f1 = (float)acce[i][1] + __log2f(h ? prod[i2][1].y : prod[i2][1].x);
            float f2 = (float)acce[i][2] + __log2f(h ? prod[i2][2].y : prod[i2][2].x);
            float f3 = (float)acce[i][3] + __log2f(h ? prod[i2][3].y : prod[i2][3].x);
            ushort4 w;
            w.x = f2bf(f0); w.y = f2bf(f1); w.z = f2bf(f2); w.w = f2bf(f3);
            *(ushort4*)&pb[(size_t)(8 * ty + i) * MM + 4 * tx] = w;
        }
}

// ---------------------------------------------------------------------------
// Kernel C: sum 16 bf16 partials + cst, per-batch logsumexp over m.
// ---------------------------------------------------------------------------
__global__ __launch_bounds__(256) void finalize_kernel(
        const unsigned short* __restrict__ pbuf, const float* __restrict__ cst,
        float* __restrict__ out) {
    const int lane = threadIdx.x & 63;
    const int w = threadIdx.x >> 6;
    const int b = blockIdx.x * 4 + w;

    float4 v = ((const float4*)cst)[lane];
    const ushort4* pb = (const ushort4*)pbuf + (size_t)b * (MM / 4) + lane;
    #pragma unroll
    for (int s = 0; s < SD; ++s) {
        ushort4 t = pb[(size_t)s * BATCH * (MM / 4)];
        v.x += bf2f(t.x); v.y += bf2f(t.y); v.z += bf2f(t.z); v.w += bf2f(t.w);
    }

    float mx = fmaxf(fmaxf(v.x, v.y), fmaxf(v.z, v.w));
    #pragma unroll
    for (int o = 32; o; o >>= 1) mx = fmaxf(mx, __shfl_xor(mx, o));

    float s = exp2f(v.x - mx) + exp2f(v.y - mx) + exp2f(v.z - mx) + exp2f(v.w - mx);
    #pragma unroll
    for (int o = 32; o; o >>= 1) s += __shfl_xor(s, o);

    if (lane == 0) out[b] = LN2 * (mx + __log2f(s));
}

extern "C" void kernel_launch(void* const* d_in, const int* in_sizes, int n_in,
                              void* d_out, int out_size, void* d_ws, size_t ws_size,
                              hipStream_t stream) {
    const float* x  = (const float*)d_in[0];
    const float* Wv = (const float*)d_in[1];
    const float* P  = (const float*)d_in[2];

    // ws layout: [xs 8MiB][rs 1MiB][cst 1KiB][pbuf bf16 16MiB] ~= 25 MiB
    float* ws  = (float*)d_ws;
    float* xs  = ws;
    float* rs  = xs + (size_t)NBT * SD * XS_TILE;
    float* cst = rs + (size_t)NMT * SD * RS_TILE;
    unsigned short* pbuf = (unsigned short*)(cst + MM);

    prep_kernel<<<MM + NBT * SD, 256, 0, stream>>>(x, P, Wv, xs, rs, cst);
    dim3 gB(NMT, NBT, SD);
    main_kernel<<<gB, 256, 0, stream>>>(xs, rs, pbuf);
    finalize_kernel<<<BATCH / 4, 256, 0, stream>>>(pbuf, cst, (float*)d_out);
}